// Round 12
// baseline (344.790 us; speedup 1.0000x reference)
//
#include <hip/hip_runtime.h>
#include <hip/hip_fp16.h>

#define HEADS 4
#define FDIM 128          // HEADS * HID
#define SM_EPS 1e-16f
#define NBUCKET 8
#define CELLCAP 128       // per-wave per-bucket cell; Binom(512,1/8) mean 64, +8.5 sigma
#define DEGCAP 64         // per-node slot count; Poisson(16), P(>64) < 1e-17
#define LOG2E 1.44269504088896340736f

typedef _Float16 f16x8 __attribute__((ext_vector_type(8)));
typedef float f32x4 __attribute__((ext_vector_type(4)));

// ---------- MFMA split-fp16 linear + fused attention coefficients ----------
// LDS-free: B-frags built straight from global W (64KB, L2-hot) with
// in-register split w = wh + wl. 4 waves = 1 m-tile x 4 col-quarters.
// a_s/a_d written pre-scaled by log2(e) so the gather uses exp2.
template <bool IN16>
__device__ __forceinline__ void mfma_body(
    int bid, int nblocks, const float* __restrict__ Xf,
    const __half* __restrict__ X16, const float* __restrict__ W,
    const float* __restrict__ att_s, const float* __restrict__ att_d,
    __half* __restrict__ Hh, float* __restrict__ a_s,
    float* __restrict__ a_d, int nrows, int ntiles) {
  int t = threadIdx.x;
  int nq = t >> 6;  // wave = col quarter (head) 0..3
  int lane = t & 63;
  int l15 = lane & 15, lg = lane >> 4;

  f16x8 Bh[2][4], Bl[2][4];
  float ws[2], wd[2];
  #pragma unroll
  for (int ntl = 0; ntl < 2; ++ntl) {
    int n = nq * 32 + ntl * 16 + l15;
    ws[ntl] = att_s[n] * LOG2E;
    wd[ntl] = att_d[n] * LOG2E;
    #pragma unroll
    for (int kk = 0; kk < 4; ++kk) {
      int k0 = kk * 32 + lg * 8;
      #pragma unroll
      for (int j = 0; j < 8; ++j) {
        float w = W[(k0 + j) * FDIM + n];
        _Float16 wh = (_Float16)w;
        Bh[ntl][kk][j] = wh;
        Bl[ntl][kk][j] = (_Float16)(w - (float)wh);
      }
    }
  }

  for (int mt = bid; mt < ntiles; mt += nblocks) {
    int row = mt * 16 + l15;
    int rclamp = row < nrows ? row : (nrows - 1);
    f32x4 acc[2] = {};
    #pragma unroll
    for (int kk = 0; kk < 4; ++kk) {
      int k0 = kk * 32 + lg * 8;
      f16x8 ah, al;
      if constexpr (IN16) {
        ah = *(const f16x8*)(X16 + (long)rclamp * FDIM + k0);
      } else {
        const float* xr = Xf + (long)rclamp * FDIM;
        float4 v0 = *(const float4*)(xr + k0);
        float4 v1 = *(const float4*)(xr + k0 + 4);
        float xv[8] = {v0.x, v0.y, v0.z, v0.w, v1.x, v1.y, v1.z, v1.w};
        #pragma unroll
        for (int j = 0; j < 8; ++j) {
          _Float16 hh = (_Float16)xv[j];
          ah[j] = hh;
          al[j] = (_Float16)(xv[j] - (float)hh);
        }
      }
      #pragma unroll
      for (int ntl = 0; ntl < 2; ++ntl) {
        acc[ntl] = __builtin_amdgcn_mfma_f32_16x16x32_f16(ah, Bh[ntl][kk],
                                                          acc[ntl], 0, 0, 0);
        acc[ntl] = __builtin_amdgcn_mfma_f32_16x16x32_f16(ah, Bl[ntl][kk],
                                                          acc[ntl], 0, 0, 0);
        if constexpr (!IN16)
          acc[ntl] = __builtin_amdgcn_mfma_f32_16x16x32_f16(al, Bh[ntl][kk],
                                                            acc[ntl], 0, 0, 0);
      }
    }
    // epilogue: C layout col=lane&15, row=(lane>>4)*4+reg
    #pragma unroll
    for (int r = 0; r < 4; ++r) {
      int rr = mt * 16 + lg * 4 + r;
      #pragma unroll
      for (int ntl = 0; ntl < 2; ++ntl) {
        int c = nq * 32 + ntl * 16 + l15;
        if (rr < nrows) Hh[(long)rr * FDIM + c] = __float2half(acc[ntl][r]);
      }
      float vs = acc[0][r] * ws[0] + acc[1][r] * ws[1];
      float vd = acc[0][r] * wd[0] + acc[1][r] * wd[1];
      #pragma unroll
      for (int off = 8; off >= 1; off >>= 1) {
        vs += __shfl_xor(vs, off, 64);
        vd += __shfl_xor(vd, off, 64);
      }
      if (l15 == 0 && rr < nrows) {
        a_s[(long)rr * HEADS + nq] = vs;
        a_d[(long)rr * HEADS + nq] = vd;
      }
    }
  }
}

// ---------- K1: fused [bin | zero-fill | mfma layer-1] ----------
__global__ __launch_bounds__(256) void fused_pre_kernel(
    const int* __restrict__ src, const int* __restrict__ dst,
    int2* __restrict__ cells, int* __restrict__ csize, int ne, int n,
    int* __restrict__ fill, const float* __restrict__ Xf,
    const float* __restrict__ W, const float* __restrict__ att_s,
    const float* __restrict__ att_d, __half* __restrict__ Hh,
    float* __restrict__ a_s, float* __restrict__ a_d, int nrows, int ntiles,
    int nbin, int nzero, int nmf) {
  int b = blockIdx.x;
  if (b < nbin) {
    unsigned mult = (unsigned)(((unsigned long long)NBUCKET << 32) / n + 1);
    int lane = threadIdx.x & 63, w = threadIdx.x >> 6;
    int gw = b * 4 + w;  // global wave id = cell row
    int beg = gw * 512;
    unsigned long long below = (1ull << lane) - 1;
    int run[NBUCKET];
    #pragma unroll
    for (int r = 0; r < NBUCKET; ++r) run[r] = 0;
    int2* cbase = cells + (long)gw * NBUCKET * CELLCAP;
    for (int k = 0; k < 8; ++k) {
      int i = beg + k * 64 + lane;
      bool valid = i < ne;
      int d = valid ? dst[i] : 0;
      int s = valid ? src[i] : 0;
      int bb = valid ? (int)__umulhi((unsigned)d, mult) : -1;
      int pos = 0;
      #pragma unroll
      for (int r = 0; r < NBUCKET; ++r) {
        unsigned long long mk = __ballot(bb == r);
        if (bb == r) pos = run[r] + __popcll(mk & below);
        run[r] += __popcll(mk);
      }
      if (valid && pos < CELLCAP) cbase[bb * CELLCAP + pos] = make_int2(s, d);
    }
    #pragma unroll
    for (int r = 0; r < NBUCKET; ++r)
      if (lane == r) csize[gw * NBUCKET + r] = min(run[r], CELLCAP);
    return;
  }
  b -= nbin;
  if (b < nzero) {
    for (int i = b * 256 + threadIdx.x; i < n; i += nzero * 256) fill[i] = 0;
    return;
  }
  b -= nzero;
  mfma_body<false>(b, nmf, Xf, (const __half*)nullptr, W, att_s, att_d, Hh,
                   a_s, a_d, nrows, ntiles);
}

// ---------- standalone layer-2 GEMM (fp16 input) ----------
__global__ __launch_bounds__(256) void mfma2_kernel(
    const __half* __restrict__ X16, const float* __restrict__ W,
    const float* __restrict__ att_s, const float* __restrict__ att_d,
    __half* __restrict__ Hh, float* __restrict__ a_s,
    float* __restrict__ a_d, int nrows, int ntiles) {
  mfma_body<true>(blockIdx.x, gridDim.x, (const float*)nullptr, X16, W, att_s,
                  att_d, Hh, a_s, a_d, nrows, ntiles);
}

// ---------- Phase B: per-XCD direct scatter into fixed-stride CSR ----------
__global__ void scatter_d_kernel(const int2* __restrict__ cells,
                                 const int* __restrict__ csize,
                                 int* __restrict__ fill,
                                 int* __restrict__ col, int ncell) {
  int r = blockIdx.x & 7;
  int nblk = gridDim.x >> 3;
  int bi = blockIdx.x >> 3;
  int w = threadIdx.x >> 6, lane = threadIdx.x & 63;
  for (int ci = bi * 4 + w; ci < ncell; ci += nblk * 4) {
    int cnt = csize[ci * NBUCKET + r];
    const int2* p = cells + ((long)ci * NBUCKET + r) * CELLCAP;
    for (int e = lane; e < cnt; e += 64) {
      int2 ed = p[e];
      int pos = atomicAdd(&fill[ed.y], 1);
      if (pos < DEGCAP) col[ed.y * DEGCAP + pos] = ed.x;
    }
  }
}

// ---------- fused GAT aggregation: two-phase, deep-pipelined ----------
// Phase 1 (lane = head*16 + e): one lane computes p[e,head] per 16-edge
// chunk; per-head chunk-sum via 4-step shfl_xor.
// Phase 2: ALL 16 Hh row-loads issued before any consumption (16 VMEMs in
// flight per wave -- R10's 4-deep version measured concurrency-limited at
// 2.9 TB/s with VALUBusy only 58%).
__global__ void gat_gather_kernel(const int* __restrict__ fill,
                                  const int* __restrict__ col,
                                  const __half2* __restrict__ Hh,  // [n][64]
                                  const float* __restrict__ a_s,
                                  const float* __restrict__ a_d,
                                  const float* __restrict__ bias,
                                  __half2* __restrict__ out_h,  // [n][64]
                                  int n, int do_silu) {
  int lane = threadIdx.x & 63;
  int node = blockIdx.x * (blockDim.x >> 6) + (threadIdx.x >> 6);
  if (node >= n) return;
  int deg = min(fill[node], DEGCAP);
  int head = lane >> 4;       // phase-1 h AND accumulate head (same layout)
  int e16 = lane & 15;        // phase-1 edge slot
  float ad = a_d[node * HEADS + head];
  const int* cbase = col + node * DEGCAP;
  float acc0 = 0.f, acc1 = 0.f, ssum = 0.f;
  int pbase = lane & 48;  // head*16

  for (int c0 = 0; c0 < deg; c0 += 16) {
    int cnt = min(16, deg - c0);
    bool act = e16 < cnt;
    // phase 1: p[e, head] in lane head*16+e (s replicated across head groups)
    int s = act ? cbase[c0 + e16] : 0;
    float asv = act ? a_s[s * HEADS + head] : 0.f;
    float x = asv + ad;
    float p = act ? exp2f(fmaxf(x, 0.2f * x)) : 0.f;
    float ps = p;
    ps += __shfl_xor(ps, 1, 64);
    ps += __shfl_xor(ps, 2, 64);
    ps += __shfl_xor(ps, 4, 64);
    ps += __shfl_xor(ps, 8, 64);
    ssum += ps;  // every lane now holds its head's chunk sum
    // phase 2
    if (cnt == 16) {
      __half2 hv[16];
      float pe[16];
      #pragma unroll
      for (int ee = 0; ee < 16; ++ee) {
        int se = __shfl(s, ee, 64);
        hv[ee] = Hh[se * 64 + lane];  // issue all 16 row-loads up front
        pe[ee] = __shfl(p, pbase + ee, 64);
      }
      #pragma unroll
      for (int ee = 0; ee < 16; ++ee) {
        float2 f = __half22float2(hv[ee]);
        acc0 += pe[ee] * f.x;
        acc1 += pe[ee] * f.y;
      }
    } else {
      int ee = 0;
      for (; ee + 4 <= cnt; ee += 4) {
        int se0 = __shfl(s, ee, 64);
        int se1 = __shfl(s, ee + 1, 64);
        int se2 = __shfl(s, ee + 2, 64);
        int se3 = __shfl(s, ee + 3, 64);
        float p0 = __shfl(p, pbase + ee, 64);
        float p1 = __shfl(p, pbase + ee + 1, 64);
        float p2 = __shfl(p, pbase + ee + 2, 64);
        float p3 = __shfl(p, pbase + ee + 3, 64);
        __half2 h0 = Hh[se0 * 64 + lane];
        __half2 h1 = Hh[se1 * 64 + lane];
        __half2 h2 = Hh[se2 * 64 + lane];
        __half2 h3 = Hh[se3 * 64 + lane];
        float2 f0 = __half22float2(h0), f1 = __half22float2(h1);
        float2 f2 = __half22float2(h2), f3 = __half22float2(h3);
        acc0 += p0 * f0.x + p1 * f1.x + p2 * f2.x + p3 * f3.x;
        acc1 += p0 * f0.y + p1 * f1.y + p2 * f2.y + p3 * f3.y;
      }
      for (; ee < cnt; ++ee) {
        int se = __shfl(s, ee, 64);
        float pev = __shfl(p, pbase + ee, 64);
        float2 f = __half22float2(Hh[se * 64 + lane]);
        acc0 += pev * f.x;
        acc1 += pev * f.y;
      }
    }
  }

  float inv = 1.f / (ssum + SM_EPS);
  float2 b2 = *(const float2*)(bias + 2 * lane);
  float o0 = acc0 * inv + b2.x;
  float o1 = acc1 * inv + b2.y;
  if (do_silu) {
    o0 = o0 / (1.f + __expf(-o0));
    o1 = o1 / (1.f + __expf(-o1));
  }
  out_h[node * 64 + lane] = __floats2half2_rn(o0, o1);
}

// ---------- DistMult decoder (fp16 embeddings, f32 rel) ----------
__global__ void decoder_kernel(const __half2* __restrict__ emb_h,  // [n][64]
                               const float* __restrict__ rel_emb,
                               const int* __restrict__ hd,
                               const int* __restrict__ rl,
                               const int* __restrict__ tl,
                               float* __restrict__ out, int nq) {
  int lane = threadIdx.x & 63;
  int q = blockIdx.x * (blockDim.x >> 6) + (threadIdx.x >> 6);
  if (q >= nq) return;
  int h = hd[q], r = rl[q], t = tl[q];
  float2 eh = __half22float2(emb_h[(long)h * 64 + lane]);
  float2 et = __half22float2(emb_h[(long)t * 64 + lane]);
  float2 er = *(const float2*)(rel_emb + (long)r * FDIM + 2 * lane);
  float acc = eh.x * er.x * et.x + eh.y * er.y * et.y;
  #pragma unroll
  for (int off = 32; off > 0; off >>= 1) acc += __shfl_down(acc, off, 64);
  if (lane == 0) out[q] = 1.f / (1.f + __expf(-acc));
}

// ---------- host side ----------
extern "C" void kernel_launch(void* const* d_in, const int* in_sizes, int n_in,
                              void* d_out, int out_size, void* d_ws,
                              size_t ws_size, hipStream_t stream) {
  const float* x    = (const float*)d_in[0];
  const int*   esrc = (const int*)d_in[1];
  const int*   edst = (const int*)d_in[2];
  const int*   hidx = (const int*)d_in[3];
  const int*   rel  = (const int*)d_in[4];
  const int*   tidx = (const int*)d_in[5];
  const float* W1   = (const float*)d_in[6];
  const float* b1   = (const float*)d_in[7];
  const float* as1  = (const float*)d_in[8];
  const float* ad1  = (const float*)d_in[9];
  const float* W2   = (const float*)d_in[10];
  const float* b2   = (const float*)d_in[11];
  const float* as2  = (const float*)d_in[12];
  const float* ad2  = (const float*)d_in[13];
  const float* remb = (const float*)d_in[14];
  float* out = (float*)d_out;

  const int N_ = in_sizes[0] / FDIM;
  const int E_ = in_sizes[1];
  const int Q_ = in_sizes[3];

  const int nbin = (E_ + 2047) / 2048;
  const int ncell = nbin * 4;  // one cell row per wave (512 edges)

  // workspace layout
  __half* Hh     = (__half*)d_ws;                      // N*128 (gemm out)
  __half* h1_h   = Hh + (long)N_ * FDIM;               // N*128 (layer1 out)
  __half* emb_h  = h1_h + (long)N_ * FDIM;             // N*128 (layer2 out)
  float*  a_s    = (float*)(emb_h + (long)N_ * FDIM);  // N*4
  float*  a_d    = a_s + (long)N_ * HEADS;             // N*4
  int*    fill   = (int*)(a_d + (long)N_ * HEADS);     // N
  int*    col    = fill + N_;                          // N*DEGCAP
  int2*   cells  = (int2*)(col + (long)N_ * DEGCAP);   // ncell*8*128 pairs
  int*    csize  = (int*)(cells + (long)ncell * NBUCKET * CELLCAP);  // ncell*8

  const int ZD = 32, MF = 1024;
  const int ntiles = (N_ + 15) / 16;

  // K1: bin + zero-fill + layer-1 GEMM, fused (independent roots overlap)
  fused_pre_kernel<<<nbin + ZD + MF, 256, 0, stream>>>(
      esrc, edst, cells, csize, E_, N_, fill, x, W1, as1, ad1, Hh, a_s, a_d,
      N_, ntiles, nbin, ZD, MF);
  scatter_d_kernel<<<2048, 256, 0, stream>>>(cells, csize, fill, col, ncell);
  gat_gather_kernel<<<(N_ + 3) / 4, 256, 0, stream>>>(
      fill, col, (const __half2*)Hh, a_s, a_d, b1, (__half2*)h1_h, N_, 1);
  mfma2_kernel<<<MF, 256, 0, stream>>>(h1_h, W2, as2, ad2, Hh, a_s, a_d, N_,
                                       ntiles);
  gat_gather_kernel<<<(N_ + 3) / 4, 256, 0, stream>>>(
      fill, col, (const __half2*)Hh, a_s, a_d, b2, (__half2*)emb_h, N_, 0);
  decoder_kernel<<<(Q_ + 3) / 4, 256, 0, stream>>>(
      (const __half2*)emb_h, remb, hidx, rel, tidx, out, Q_);
}

// Round 13
// 303.489 us; speedup vs baseline: 1.1361x; 1.1361x over previous
//
#include <hip/hip_runtime.h>
#include <hip/hip_fp16.h>

#define HEADS 4
#define FDIM 128          // HEADS * HID
#define SM_EPS 1e-16f
#define NBUCKET 8
#define CELLCAP 128       // per-wave per-bucket cell; Binom(512,1/8) mean 64, +8.5 sigma
#define DEGCAP 64         // per-node slot count; Poisson(16), P(>64) < 1e-17
#define LOG2E 1.44269504088896340736f

typedef _Float16 f16x8 __attribute__((ext_vector_type(8)));
typedef float f32x4 __attribute__((ext_vector_type(4)));

// ---------- MFMA split-fp16 linear + fused attention coefficients ----------
// LDS-free: B-frags built straight from global W (64KB, L2-hot) with
// in-register split w = wh + wl. 4 waves = 1 m-tile x 4 col-quarters.
// a_s/a_d written pre-scaled by log2(e) so the gather uses exp2.
template <bool IN16>
__device__ __forceinline__ void mfma_body(
    int bid, int nblocks, const float* __restrict__ Xf,
    const __half* __restrict__ X16, const float* __restrict__ W,
    const float* __restrict__ att_s, const float* __restrict__ att_d,
    __half* __restrict__ Hh, float* __restrict__ a_s,
    float* __restrict__ a_d, int nrows, int ntiles) {
  int t = threadIdx.x;
  int nq = t >> 6;  // wave = col quarter (head) 0..3
  int lane = t & 63;
  int l15 = lane & 15, lg = lane >> 4;

  f16x8 Bh[2][4], Bl[2][4];
  float ws[2], wd[2];
  #pragma unroll
  for (int ntl = 0; ntl < 2; ++ntl) {
    int n = nq * 32 + ntl * 16 + l15;
    ws[ntl] = att_s[n] * LOG2E;
    wd[ntl] = att_d[n] * LOG2E;
    #pragma unroll
    for (int kk = 0; kk < 4; ++kk) {
      int k0 = kk * 32 + lg * 8;
      #pragma unroll
      for (int j = 0; j < 8; ++j) {
        float w = W[(k0 + j) * FDIM + n];
        _Float16 wh = (_Float16)w;
        Bh[ntl][kk][j] = wh;
        Bl[ntl][kk][j] = (_Float16)(w - (float)wh);
      }
    }
  }

  for (int mt = bid; mt < ntiles; mt += nblocks) {
    int row = mt * 16 + l15;
    int rclamp = row < nrows ? row : (nrows - 1);
    f32x4 acc[2] = {};
    #pragma unroll
    for (int kk = 0; kk < 4; ++kk) {
      int k0 = kk * 32 + lg * 8;
      f16x8 ah, al;
      if constexpr (IN16) {
        ah = *(const f16x8*)(X16 + (long)rclamp * FDIM + k0);
      } else {
        const float* xr = Xf + (long)rclamp * FDIM;
        float4 v0 = *(const float4*)(xr + k0);
        float4 v1 = *(const float4*)(xr + k0 + 4);
        float xv[8] = {v0.x, v0.y, v0.z, v0.w, v1.x, v1.y, v1.z, v1.w};
        #pragma unroll
        for (int j = 0; j < 8; ++j) {
          _Float16 hh = (_Float16)xv[j];
          ah[j] = hh;
          al[j] = (_Float16)(xv[j] - (float)hh);
        }
      }
      #pragma unroll
      for (int ntl = 0; ntl < 2; ++ntl) {
        acc[ntl] = __builtin_amdgcn_mfma_f32_16x16x32_f16(ah, Bh[ntl][kk],
                                                          acc[ntl], 0, 0, 0);
        acc[ntl] = __builtin_amdgcn_mfma_f32_16x16x32_f16(ah, Bl[ntl][kk],
                                                          acc[ntl], 0, 0, 0);
        if constexpr (!IN16)
          acc[ntl] = __builtin_amdgcn_mfma_f32_16x16x32_f16(al, Bh[ntl][kk],
                                                            acc[ntl], 0, 0, 0);
      }
    }
    // epilogue: C layout col=lane&15, row=(lane>>4)*4+reg
    #pragma unroll
    for (int r = 0; r < 4; ++r) {
      int rr = mt * 16 + lg * 4 + r;
      #pragma unroll
      for (int ntl = 0; ntl < 2; ++ntl) {
        int c = nq * 32 + ntl * 16 + l15;
        if (rr < nrows) Hh[(long)rr * FDIM + c] = __float2half(acc[ntl][r]);
      }
      float vs = acc[0][r] * ws[0] + acc[1][r] * ws[1];
      float vd = acc[0][r] * wd[0] + acc[1][r] * wd[1];
      #pragma unroll
      for (int off = 8; off >= 1; off >>= 1) {
        vs += __shfl_xor(vs, off, 64);
        vd += __shfl_xor(vd, off, 64);
      }
      if (l15 == 0 && rr < nrows) {
        a_s[(long)rr * HEADS + nq] = vs;
        a_d[(long)rr * HEADS + nq] = vd;
      }
    }
  }
}

// ---------- K1': fused [bin | zero-fill] ----------
// bin: per-wave 512 edges -> private cells (ballot-rank, no atomics).
__global__ __launch_bounds__(256) void fused_bin_kernel(
    const int* __restrict__ src, const int* __restrict__ dst,
    int2* __restrict__ cells, int* __restrict__ csize, int ne, int n,
    int* __restrict__ fill, int nbin, int nzero) {
  int b = blockIdx.x;
  if (b < nbin) {
    unsigned mult = (unsigned)(((unsigned long long)NBUCKET << 32) / n + 1);
    int lane = threadIdx.x & 63, w = threadIdx.x >> 6;
    int gw = b * 4 + w;  // global wave id = cell row
    int beg = gw * 512;
    unsigned long long below = (1ull << lane) - 1;
    int run[NBUCKET];
    #pragma unroll
    for (int r = 0; r < NBUCKET; ++r) run[r] = 0;
    int2* cbase = cells + (long)gw * NBUCKET * CELLCAP;
    for (int k = 0; k < 8; ++k) {
      int i = beg + k * 64 + lane;
      bool valid = i < ne;
      int d = valid ? dst[i] : 0;
      int s = valid ? src[i] : 0;
      int bb = valid ? (int)__umulhi((unsigned)d, mult) : -1;
      int pos = 0;
      #pragma unroll
      for (int r = 0; r < NBUCKET; ++r) {
        unsigned long long mk = __ballot(bb == r);
        if (bb == r) pos = run[r] + __popcll(mk & below);
        run[r] += __popcll(mk);
      }
      if (valid && pos < CELLCAP) cbase[bb * CELLCAP + pos] = make_int2(s, d);
    }
    #pragma unroll
    for (int r = 0; r < NBUCKET; ++r)
      if (lane == r) csize[gw * NBUCKET + r] = min(run[r], CELLCAP);
    return;
  }
  b -= nbin;
  for (int i = b * 256 + threadIdx.x; i < n; i += nzero * 256) fill[i] = 0;
}

// ---------- K2': fused [mfma layer-1 | per-XCD scatter] ----------
// Blocks [0,nmf): layer-1 GEMM (MFMA-pipe-bound). Blocks [nmf,..): direct
// scatter into fixed-stride CSR (atomic-latency-bound). Co-resident, the
// two roles overlap pipes instead of serializing. nmf % 8 == 0 keeps the
// scatter's blockIdx&7 -> XCD slice mapping intact.
__global__ __launch_bounds__(256) void fused_mid_kernel(
    const int2* __restrict__ cells, const int* __restrict__ csize,
    int* __restrict__ fill, int* __restrict__ col, int ncell,
    const float* __restrict__ Xf, const float* __restrict__ W,
    const float* __restrict__ att_s, const float* __restrict__ att_d,
    __half* __restrict__ Hh, float* __restrict__ a_s,
    float* __restrict__ a_d, int nrows, int ntiles, int nmf) {
  int b = blockIdx.x;
  if (b < nmf) {
    mfma_body<false>(b, nmf, Xf, (const __half*)nullptr, W, att_s, att_d, Hh,
                     a_s, a_d, nrows, ntiles);
    return;
  }
  int sb = b - nmf;
  int r = sb & 7;  // == b&7 since nmf%8==0
  int nblk = (gridDim.x - nmf) >> 3;
  int bi = sb >> 3;
  int w = threadIdx.x >> 6, lane = threadIdx.x & 63;
  for (int ci = bi * 4 + w; ci < ncell; ci += nblk * 4) {
    int cnt = csize[ci * NBUCKET + r];
    const int2* p = cells + ((long)ci * NBUCKET + r) * CELLCAP;
    for (int e = lane; e < cnt; e += 64) {
      int2 ed = p[e];
      int pos = atomicAdd(&fill[ed.y], 1);
      if (pos < DEGCAP) col[ed.y * DEGCAP + pos] = ed.x;
    }
  }
}

// ---------- standalone layer-2 GEMM (fp16 input) ----------
__global__ __launch_bounds__(256) void mfma2_kernel(
    const __half* __restrict__ X16, const float* __restrict__ W,
    const float* __restrict__ att_s, const float* __restrict__ att_d,
    __half* __restrict__ Hh, float* __restrict__ a_s,
    float* __restrict__ a_d, int nrows, int ntiles) {
  mfma_body<true>(blockIdx.x, gridDim.x, (const float*)nullptr, X16, W, att_s,
                  att_d, Hh, a_s, a_d, nrows, ntiles);
}

// ---------- fused GAT aggregation: two-phase, one wave per node ----------
// (R10 version -- R11's 16-deep ILP variant cost occupancy 70->46% and
// regressed 80->104 us; TLP is the concurrency source here.)
// Phase 1 (lane = head*16 + e): one lane computes p[e,head] per 16-edge
// chunk; per-head chunk-sum via 4-step shfl_xor.
// Phase 2: per edge, broadcast (s, p) via shuffles and do the 2-channel FMA.
__global__ void gat_gather_kernel(const int* __restrict__ fill,
                                  const int* __restrict__ col,
                                  const __half2* __restrict__ Hh,  // [n][64]
                                  const float* __restrict__ a_s,
                                  const float* __restrict__ a_d,
                                  const float* __restrict__ bias,
                                  __half2* __restrict__ out_h,  // [n][64]
                                  int n, int do_silu) {
  int lane = threadIdx.x & 63;
  int node = blockIdx.x * (blockDim.x >> 6) + (threadIdx.x >> 6);
  if (node >= n) return;
  int deg = min(fill[node], DEGCAP);
  int head = lane >> 4;       // phase-1 h AND accumulate head (same layout)
  int e16 = lane & 15;        // phase-1 edge slot
  float ad = a_d[node * HEADS + head];
  const int* cbase = col + node * DEGCAP;
  float acc0 = 0.f, acc1 = 0.f, ssum = 0.f;

  for (int c0 = 0; c0 < deg; c0 += 16) {
    int cnt = min(16, deg - c0);
    bool act = e16 < cnt;
    // phase 1: p[e, head] in lane head*16+e (s replicated across head groups)
    int s = act ? cbase[c0 + e16] : 0;
    float asv = act ? a_s[s * HEADS + head] : 0.f;
    float x = asv + ad;
    float p = act ? exp2f(fmaxf(x, 0.2f * x)) : 0.f;
    float ps = p;
    ps += __shfl_xor(ps, 1, 64);
    ps += __shfl_xor(ps, 2, 64);
    ps += __shfl_xor(ps, 4, 64);
    ps += __shfl_xor(ps, 8, 64);
    ssum += ps;  // every lane now holds its head's chunk sum
    // phase 2: accumulate alpha-weighted source rows
    int pbase = lane & 48;  // head*16
    int ee = 0;
    for (; ee + 4 <= cnt; ee += 4) {
      int se0 = __shfl(s, ee, 64);
      int se1 = __shfl(s, ee + 1, 64);
      int se2 = __shfl(s, ee + 2, 64);
      int se3 = __shfl(s, ee + 3, 64);
      float p0 = __shfl(p, pbase + ee, 64);
      float p1 = __shfl(p, pbase + ee + 1, 64);
      float p2 = __shfl(p, pbase + ee + 2, 64);
      float p3 = __shfl(p, pbase + ee + 3, 64);
      __half2 h0 = Hh[se0 * 64 + lane];
      __half2 h1 = Hh[se1 * 64 + lane];
      __half2 h2 = Hh[se2 * 64 + lane];
      __half2 h3 = Hh[se3 * 64 + lane];
      float2 f0 = __half22float2(h0), f1 = __half22float2(h1);
      float2 f2 = __half22float2(h2), f3 = __half22float2(h3);
      acc0 += p0 * f0.x + p1 * f1.x + p2 * f2.x + p3 * f3.x;
      acc1 += p0 * f0.y + p1 * f1.y + p2 * f2.y + p3 * f3.y;
    }
    for (; ee < cnt; ++ee) {
      int se = __shfl(s, ee, 64);
      float pe = __shfl(p, pbase + ee, 64);
      float2 f = __half22float2(Hh[se * 64 + lane]);
      acc0 += pe * f.x;
      acc1 += pe * f.y;
    }
  }

  float inv = 1.f / (ssum + SM_EPS);
  float2 b2 = *(const float2*)(bias + 2 * lane);
  float o0 = acc0 * inv + b2.x;
  float o1 = acc1 * inv + b2.y;
  if (do_silu) {
    o0 = o0 / (1.f + __expf(-o0));
    o1 = o1 / (1.f + __expf(-o1));
  }
  out_h[node * 64 + lane] = __floats2half2_rn(o0, o1);
}

// ---------- DistMult decoder (fp16 embeddings, f32 rel) ----------
__global__ void decoder_kernel(const __half2* __restrict__ emb_h,  // [n][64]
                               const float* __restrict__ rel_emb,
                               const int* __restrict__ hd,
                               const int* __restrict__ rl,
                               const int* __restrict__ tl,
                               float* __restrict__ out, int nq) {
  int lane = threadIdx.x & 63;
  int q = blockIdx.x * (blockDim.x >> 6) + (threadIdx.x >> 6);
  if (q >= nq) return;
  int h = hd[q], r = rl[q], t = tl[q];
  float2 eh = __half22float2(emb_h[(long)h * 64 + lane]);
  float2 et = __half22float2(emb_h[(long)t * 64 + lane]);
  float2 er = *(const float2*)(rel_emb + (long)r * FDIM + 2 * lane);
  float acc = eh.x * er.x * et.x + eh.y * er.y * et.y;
  #pragma unroll
  for (int off = 32; off > 0; off >>= 1) acc += __shfl_down(acc, off, 64);
  if (lane == 0) out[q] = 1.f / (1.f + __expf(-acc));
}

// ---------- host side ----------
extern "C" void kernel_launch(void* const* d_in, const int* in_sizes, int n_in,
                              void* d_out, int out_size, void* d_ws,
                              size_t ws_size, hipStream_t stream) {
  const float* x    = (const float*)d_in[0];
  const int*   esrc = (const int*)d_in[1];
  const int*   edst = (const int*)d_in[2];
  const int*   hidx = (const int*)d_in[3];
  const int*   rel  = (const int*)d_in[4];
  const int*   tidx = (const int*)d_in[5];
  const float* W1   = (const float*)d_in[6];
  const float* b1   = (const float*)d_in[7];
  const float* as1  = (const float*)d_in[8];
  const float* ad1  = (const float*)d_in[9];
  const float* W2   = (const float*)d_in[10];
  const float* b2   = (const float*)d_in[11];
  const float* as2  = (const float*)d_in[12];
  const float* ad2  = (const float*)d_in[13];
  const float* remb = (const float*)d_in[14];
  float* out = (float*)d_out;

  const int N_ = in_sizes[0] / FDIM;
  const int E_ = in_sizes[1];
  const int Q_ = in_sizes[3];

  const int nbin = (E_ + 2047) / 2048;
  const int ncell = nbin * 4;  // one cell row per wave (512 edges)

  // workspace layout
  __half* Hh     = (__half*)d_ws;                      // N*128 (gemm out)
  __half* h1_h   = Hh + (long)N_ * FDIM;               // N*128 (layer1 out)
  __half* emb_h  = h1_h + (long)N_ * FDIM;             // N*128 (layer2 out)
  float*  a_s    = (float*)(emb_h + (long)N_ * FDIM);  // N*4
  float*  a_d    = a_s + (long)N_ * HEADS;             // N*4
  int*    fill   = (int*)(a_d + (long)N_ * HEADS);     // N
  int*    col    = fill + N_;                          // N*DEGCAP
  int2*   cells  = (int2*)(col + (long)N_ * DEGCAP);   // ncell*8*128 pairs
  int*    csize  = (int*)(cells + (long)ncell * NBUCKET * CELLCAP);  // ncell*8

  const int ZD = 32, MF = 1024, SC = 2048;
  const int ntiles = (N_ + 15) / 16;

  // K1': bin + zero-fill (both streaming, independent)
  fused_bin_kernel<<<nbin + ZD, 256, 0, stream>>>(esrc, edst, cells, csize,
                                                  E_, N_, fill, nbin, ZD);
  // K2': layer-1 GEMM overlapped with per-XCD scatter
  fused_mid_kernel<<<MF + SC, 256, 0, stream>>>(
      cells, csize, fill, col, ncell, x, W1, as1, ad1, Hh, a_s, a_d, N_,
      ntiles, MF);
  gat_gather_kernel<<<(N_ + 3) / 4, 256, 0, stream>>>(
      fill, col, (const __half2*)Hh, a_s, a_d, b1, (__half2*)h1_h, N_, 1);
  mfma2_kernel<<<MF, 256, 0, stream>>>(h1_h, W2, as2, ad2, Hh, a_s, a_d, N_,
                                       ntiles);
  gat_gather_kernel<<<(N_ + 3) / 4, 256, 0, stream>>>(
      fill, col, (const __half2*)Hh, a_s, a_d, b2, (__half2*)emb_h, N_, 0);
  decoder_kernel<<<(Q_ + 3) / 4, 256, 0, stream>>>(
      (const __half2*)emb_h, remb, hidx, rel, tidx, out, Q_);
}